// Round 2
// baseline (331.146 us; speedup 1.0000x reference)
//
#include <hip/hip_runtime.h>
#include <hip/hip_bf16.h>
#include <stdint.h>

#define BB 256
#define TT 240
#define CC 512
#define KK 64
#define NCLS 4
#define THREADS 1024

// ---------------- main-kernel (split-T) geometry ----------------
#define THALF 120
#define NCH1 8          // 7 full chunks of 16 + 1 chunk of 8 per half
// Subtiled x layout: x[tb][cb][4][16] bf16, tb=t/4 (4 per chunk), cb=c/16 (32)
#define CBS 64          // elems per c-block (128 B, no pad)
#define TBS 2056        // elems per t-block: 32*64 + 8 pad (bank offset ≡ 4 mod 32)
#define XELEMS (4*TBS)  // 8224 elems = 16448 B per buffer

typedef __attribute__((ext_vector_type(8))) short bf16x8;
typedef __attribute__((ext_vector_type(4))) float f32x4;
typedef __attribute__((ext_vector_type(2))) unsigned int u32x2;

__device__ __forceinline__ unsigned short f2bf(float f) {
    union { float f; unsigned int i; } x; x.f = f;
    unsigned int r = x.i + 0x7FFFu + ((x.i >> 16) & 1u);  // RNE, finite only
    return (unsigned short)(r >> 16);
}
__device__ __forceinline__ unsigned int pk2cvt(float lo, float hi) {
    union { __hip_bfloat162 h; unsigned int u; } c;
    c.h = __float22bfloat162_rn(float2{lo, hi});
    return c.u;
}
// LDS-only barrier: doesn't drain vmcnt (global prefetch stays in flight)
__device__ __forceinline__ void LB() {
    asm volatile("s_waitcnt lgkmcnt(0)\n\ts_barrier" ::: "memory");
}

// ================= kernel 1: main loop (one T-half per block) =================
struct alignas(16) SMem1 {
    unsigned short x[3][XELEMS];    // triple-buffered subtiled x  (49,344 B)
    float logitsP[4][16][67];       // k-quarter partials / a      (17,152 B)
    unsigned short aT[KK][40];      // a' = a*rinv bf16, 32 t/pair ( 5,120 B)
    float sumsqP[2][16][16];        // 4-folded sumsq partials     ( 2,048 B)
    float asumP[4][KK];             // per-wave asum accumulators  ( 1,024 B)
};                                  // ~73 KB -> 2 blocks/CU

__device__ __forceinline__ void stage_chunk(SMem1* sm, float4 u0, float4 u1,
        int t_s, int c8, int lane, int tv, int buf, int sbuf) {
    uint4 val = (uint4){pk2cvt(u0.x, u0.y), pk2cvt(u0.z, u0.w),
                        pk2cvt(u1.x, u1.y), pk2cvt(u1.z, u1.w)};
    float s = u0.x*u0.x + u0.y*u0.y + u0.z*u0.z + u0.w*u0.w
            + u1.x*u1.x + u1.y*u1.y + u1.z*u1.z + u1.w*u1.w;
    if (t_s >= tv) { val = (uint4){0u,0u,0u,0u}; s = 0.f; }
    int off = (t_s >> 2) * TBS + (c8 >> 4) * CBS + (t_s & 3) * 16 + (c8 & 15);
    *(uint4*)&sm->x[buf][off] = val;
    s += __shfl_xor(s, 16); s += __shfl_xor(s, 32);
    if (lane < 16) sm->sumsqP[sbuf][t_s][lane] = s;   // 16 partials per row
}

__global__ __launch_bounds__(THREADS, 8) void netvlad_main(
    const float* __restrict__ inp,    // [B,T,C]
    const float* __restrict__ convw,  // [K,C]
    float* __restrict__ wsv,          // [512][K*C] partial vlad
    float* __restrict__ wsa)          // [512][K]   partial asum
{
    __shared__ SMem1 sm;

    const int tid  = threadIdx.x;
    const int blk  = blockIdx.x;
    const int b    = blk >> 1;
    const int half = blk & 1;
    const int w    = tid >> 6;
    const int lane = tid & 63;
    const int grp  = (lane >> 4) & 3;
    const int col  = lane & 15;
    const int cg   = w & 3;          // cluster group (logits A / VLAD A)
    const int kh   = w >> 2;         // logits k-quarter (0..3)
    const int cq   = w >> 2;         // VLAD c-quarter (0..3)

    if (tid < 256) ((float*)sm.asumP)[tid] = 0.f;

    f32x4 acc[8];
    #pragma unroll
    for (int j = 0; j < 8; ++j) acc[j] = (f32x4){0.f, 0.f, 0.f, 0.f};

    // conv_w slice: clusters 16cg..+16, k-quarter kh (4 x bf16x8 = 8 VGPRs)
    bf16x8 cw[4];
    #pragma unroll
    for (int s = 0; s < 4; ++s) {
        const float* p = convw + (size_t)(cg * 16 + col) * CC + (kh * 4 + s) * 32 + grp * 8;
        float4 a0 = *(const float4*)p;
        float4 a1 = *(const float4*)(p + 4);
        bf16x8 v;
        v[0] = (short)f2bf(a0.x); v[1] = (short)f2bf(a0.y);
        v[2] = (short)f2bf(a0.z); v[3] = (short)f2bf(a0.w);
        v[4] = (short)f2bf(a1.x); v[5] = (short)f2bf(a1.y);
        v[6] = (short)f2bf(a1.z); v[7] = (short)f2bf(a1.w);
        cw[s] = v;
    }

    const size_t ibase = (size_t)b * (TT * CC);
    const int tbase = half * THALF;
    const int t_s = tid >> 6;          // staging row (wave-uniform)
    const int c8  = lane << 3;         // staging col (8 floats)

    float4 r0, r1;
    // prologue: load+stage chunk 0, prefetch chunk 1
    {
        int tg = tbase + t_s;
        const float* p = inp + ibase + (size_t)tg * CC + c8;
        float4 u0 = *(const float4*)p, u1 = *(const float4*)(p + 4);
        stage_chunk(&sm, u0, u1, t_s, c8, lane, 16, 0, 0);
    }
    {
        int tg = tbase + 16 + t_s;
        const float* p = inp + ibase + (size_t)tg * CC + c8;
        r0 = *(const float4*)p; r1 = *(const float4*)(p + 4);
    }
    LB();

    int bufc = 0, bufp = 2;
    for (int ch = 0; ch < NCH1; ++ch) {
        int bufn = bufc + 1; if (bufn == 3) bufn = 0;
        const int tv = (THALF - ch * 16 > 16) ? 16 : (THALF - ch * 16);

        // ---- stage chunk ch+1 (regs->LDS), prefetch chunk ch+2; overlapped with B ----
        if (ch + 1 < NCH1) {
            int tvn = THALF - (ch + 1) * 16; if (tvn > 16) tvn = 16;
            stage_chunk(&sm, r0, r1, t_s, c8, lane, tvn, bufn, (ch + 1) & 1);
        }
        if (ch + 2 < NCH1) {
            int tg = tbase + (ch + 2) * 16 + t_s; if (tg > TT - 1) tg = TT - 1;
            const float* p = inp + ibase + (size_t)tg * CC + c8;
            r0 = *(const float4*)p; r1 = *(const float4*)(p + 4);
        }

        // ---- B: logits partials for chunk ch (all 16 waves) ----
        {
            const unsigned short* xb = sm.x[bufc];
            f32x4 lt = (f32x4){0.f, 0.f, 0.f, 0.f};
            const int rb = (col >> 2) * TBS + (col & 3) * 16 + (grp & 1) * 8;
            #pragma unroll
            for (int s = 0; s < 4; ++s) {
                int cb = (kh * 4 + s) * 2 + (grp >> 1);
                bf16x8 bb = *(const bf16x8*)&xb[rb + cb * CBS];
                lt = __builtin_amdgcn_mfma_f32_16x16x32_bf16(cw[s], bb, lt, 0, 0, 0);
            }
            #pragma unroll
            for (int r = 0; r < 4; ++r)
                sm.logitsP[kh][col][cg * 16 + grp * 4 + r] = lt[r];
        }
        LB();  // x(ch+1) staged + logitsP(ch) ready

        // ---- C: sumsq finish + softmax + asum partials (tid<256) ----
        if (tid < 256) {
            int t = tid >> 4, part = tid & 15;
            float ss = sm.sumsqP[ch & 1][t][part];
            float l[4]; float lmax = -1e30f;
            #pragma unroll
            for (int q = 0; q < 4; ++q) {
                int c = q * 16 + part;
                l[q] = sm.logitsP[0][t][c] + sm.logitsP[1][t][c]
                     + sm.logitsP[2][t][c] + sm.logitsP[3][t][c];
                lmax = fmaxf(lmax, l[q]);
            }
            #pragma unroll
            for (int m = 1; m < 16; m <<= 1) {
                lmax = fmaxf(lmax, __shfl_xor(lmax, m));
                ss  += __shfl_xor(ss, m);
            }
            float rinv = 1.f / fmaxf(sqrtf(ss), 1e-12f);
            rinv = (t < tv) ? rinv : 0.f;
            float m0 = lmax * rinv;
            float es = 0.f;
            #pragma unroll
            for (int q = 0; q < 4; ++q) { l[q] = __expf(l[q] * rinv - m0); es += l[q]; }
            #pragma unroll
            for (int m = 1; m < 16; m <<= 1) es += __shfl_xor(es, m);
            float is = 1.f / es;
            int tofs = (ch & 1) * 16;
            float am[4];
            #pragma unroll
            for (int q = 0; q < 4; ++q) {
                float a = l[q] * is;
                sm.aT[q * 16 + part][tofs + t] = (unsigned short)f2bf(a * rinv);
                am[q] = (t < tv) ? a : 0.f;
            }
            #pragma unroll
            for (int q = 0; q < 4; ++q) { am[q] += __shfl_xor(am[q], 16); am[q] += __shfl_xor(am[q], 32); }
            if (lane < 16) {
                #pragma unroll
                for (int q = 0; q < 4; ++q) sm.asumP[w][q * 16 + lane] += am[q];
            }
        }
        LB();  // aT(ch half) ready

        // ---- D (odd ch): VLAD over the pair (K=32) via HW transpose reads ----
        if (ch & 1) {
            bf16x8 af = *(const bf16x8*)&sm.aT[cg * 16 + col][grp * 8];
            // grp 0,1 -> even-chunk buffer (bufp); grp 2,3 -> odd (bufc)
            unsigned bsel = (grp >> 1) ? (unsigned)bufc : (unsigned)bufp;
            unsigned base = (unsigned)(uintptr_t)&sm.x[0][0]
                + (bsel * (unsigned)XELEMS
                   + (unsigned)(((grp & 1) * 2) * TBS + (cq * 8) * CBS + col)) * 2u;
            #pragma unroll
            for (int hh = 0; hh < 2; ++hh) {
                u32x2 lo[4], hi[4];
                #pragma unroll
                for (int j2 = 0; j2 < 4; ++j2) {
                    unsigned o = base + (unsigned)((hh * 4 + j2) * (2 * CBS));
                    asm volatile("ds_read_b64_tr_b16 %0, %1" : "=v"(lo[j2]) : "v"(o));
                    asm volatile("ds_read_b64_tr_b16 %0, %1" : "=v"(hi[j2]) : "v"(o + (unsigned)(2 * TBS)));
                }
                asm volatile("s_waitcnt lgkmcnt(0)" ::: "memory");
                __builtin_amdgcn_sched_barrier(0);
                #pragma unroll
                for (int j2 = 0; j2 < 4; ++j2) {
                    union { bf16x8 v; u32x2 u[2]; } pk;
                    pk.u[0] = lo[j2]; pk.u[1] = hi[j2];
                    acc[hh * 4 + j2] = __builtin_amdgcn_mfma_f32_16x16x32_bf16(
                        af, pk.v, acc[hh * 4 + j2], 0, 0, 0);
                }
            }
            LB();  // protects x bufs + aT before reuse
        }
        bufp = bufc; bufc = bufn;
    }

    // ---- write partials ----
    if (tid < KK) {
        float a = sm.asumP[0][tid] + sm.asumP[1][tid] + sm.asumP[2][tid] + sm.asumP[3][tid];
        wsa[blk * KK + tid] = a;
    }
    float* wv = wsv + (size_t)blk * (KK * CC);
    #pragma unroll
    for (int r = 0; r < 4; ++r) {
        int cl = cg * 16 + grp * 4 + r;
        #pragma unroll
        for (int j = 0; j < 8; ++j)
            wv[cl * CC + cq * 128 + j * 16 + col] = acc[j][r];
    }
}

// ================= kernel 2: combine + normalize + FC =================
struct alignas(16) SMem2 {
    unsigned short vbuf[KK][520];   // padded rows (66,560 B)
    float gred[16];
    float fcred[16][NCLS];
    float vinv;
};

__global__ __launch_bounds__(THREADS) void netvlad_epi(
    const float* __restrict__ wsv, const float* __restrict__ wsa,
    const float* __restrict__ cent, const float* __restrict__ fcw,
    const float* __restrict__ fcb, float* __restrict__ out)
{
    __shared__ SMem2 sm;
    const int tid = threadIdx.x, b = blockIdx.x;
    const int w = tid >> 6, lane = tid & 63;
    const int cl = tid >> 4, part = tid & 15, c0 = part * 32;

    const float* v0 = wsv + (size_t)(2 * b) * (KK * CC) + (size_t)cl * CC + c0;
    const float* v1 = v0 + KK * CC;
    const float* cp = cent + (size_t)cl * CC + c0;
    float as = wsa[(2 * b) * KK + cl] + wsa[(2 * b + 1) * KK + cl];

    float v[32]; float ss = 0.f;
    #pragma unroll
    for (int i = 0; i < 8; ++i) {
        float4 a  = *(const float4*)(v0 + 4 * i);
        float4 bq = *(const float4*)(v1 + 4 * i);
        float4 c4 = *(const float4*)(cp + 4 * i);
        float x0 = a.x + bq.x - as * c4.x;
        float x1 = a.y + bq.y - as * c4.y;
        float x2 = a.z + bq.z - as * c4.z;
        float x3 = a.w + bq.w - as * c4.w;
        v[4*i] = x0; v[4*i+1] = x1; v[4*i+2] = x2; v[4*i+3] = x3;
        ss += x0*x0 + x1*x1 + x2*x2 + x3*x3;
    }
    #pragma unroll
    for (int m = 1; m < 16; m <<= 1) ss += __shfl_xor(ss, m);
    float inv = 1.f / fmaxf(sqrtf(ss), 1e-12f);
    float contrib = 0.f;
    #pragma unroll
    for (int i = 0; i < 32; ++i) { v[i] *= inv; contrib += v[i] * v[i]; }
    #pragma unroll
    for (int m = 1; m < 64; m <<= 1) contrib += __shfl_xor(contrib, m);
    if (lane == 0) sm.gred[w] = contrib;
    __syncthreads();
    if (tid == 0) {
        float tot = 0.f;
        #pragma unroll
        for (int i = 0; i < 16; ++i) tot += sm.gred[i];
        sm.vinv = 1.f / fmaxf(sqrtf(tot), 1e-12f);
    }
    __syncthreads();
    {
        float vinv = sm.vinv;
        #pragma unroll
        for (int i = 0; i < 4; ++i) {
            uint4 pv = (uint4){ pk2cvt(v[8*i]*vinv,   v[8*i+1]*vinv),
                                pk2cvt(v[8*i+2]*vinv, v[8*i+3]*vinv),
                                pk2cvt(v[8*i+4]*vinv, v[8*i+5]*vinv),
                                pk2cvt(v[8*i+6]*vinv, v[8*i+7]*vinv) };
            *(uint4*)&sm.vbuf[cl][c0 + 8 * i] = pv;
        }
    }
    __syncthreads();

    float pacc[NCLS] = {0.f, 0.f, 0.f, 0.f};
    #pragma unroll
    for (int i = 0; i < 4; ++i) {
        int idx = i * 8192 + tid * 8;
        int row = idx >> 9, off = idx & 511;
        bf16x8 vv = *(const bf16x8*)&sm.vbuf[row][off];
        float vf[8];
        #pragma unroll
        for (int h = 0; h < 8; ++h) {
            union { unsigned int u; float f; } cvt;
            cvt.u = ((unsigned int)(unsigned short)vv[h]) << 16;
            vf[h] = cvt.f;
        }
        #pragma unroll
        for (int nc = 0; nc < NCLS; ++nc) {
            const float* wp = fcw + (size_t)nc * (KK * CC) + idx;
            float4 w0 = *(const float4*)wp;
            float4 w1 = *(const float4*)(wp + 4);
            pacc[nc] += vf[0]*w0.x + vf[1]*w0.y + vf[2]*w0.z + vf[3]*w0.w
                      + vf[4]*w1.x + vf[5]*w1.y + vf[6]*w1.z + vf[7]*w1.w;
        }
    }
    #pragma unroll
    for (int nc = 0; nc < NCLS; ++nc) {
        #pragma unroll
        for (int m = 1; m < 64; m <<= 1) pacc[nc] += __shfl_xor(pacc[nc], m);
    }
    if (lane == 0) {
        #pragma unroll
        for (int nc = 0; nc < NCLS; ++nc) sm.fcred[w][nc] = pacc[nc];
    }
    __syncthreads();
    if (tid < NCLS) {
        float s = fcb[tid];
        #pragma unroll
        for (int ww = 0; ww < 16; ++ww) s += sm.fcred[ww][tid];
        out[b * NCLS + tid] = 1.f / (1.f + __expf(-s));
    }
}

// ================= fallback: previous verified single kernel =================
#define CHUNK 32
#define NCHUNK 8
#define FCBS 72
#define FTBS 2312
#define FXELEMS (8 * FTBS)

struct alignas(16) SMemChunkF {
    unsigned short x[2][FXELEMS];
    float logitsP[2][CHUNK][67];
    unsigned short aT[KK][40];
    float sumsqP[CHUNK][68];
};
struct alignas(16) SMemEpiF { unsigned short vbuf[KK * CC]; };
union SMemUF { SMemChunkF c; SMemEpiF e; };

__global__ __launch_bounds__(THREADS, 4) void netvlad_fallback(
    const float* __restrict__ inp, const float* __restrict__ convw,
    const float* __restrict__ cent, const float* __restrict__ fcw,
    const float* __restrict__ fcb, float* __restrict__ out)
{
    __shared__ SMemUF sm;
    __shared__ float asum[KK];
    __shared__ float ssred[4][KK];
    __shared__ float gred[16];
    __shared__ float fcred[16][NCLS];
    __shared__ float vinv_sh;

    const int tid  = threadIdx.x;
    const int b    = blockIdx.x;
    const int w    = tid >> 6;
    const int lane = tid & 63;
    const int grp  = (lane >> 4) & 3;
    const int col  = lane & 15;
    const int cg   = w & 3;
    const int th   = (w >> 2) & 1;
    const int kh   = w >> 3;
    const int cq   = w >> 2;

    if (tid < KK) asum[tid] = 0.f;

    f32x4 acc[8];
    #pragma unroll
    for (int j = 0; j < 8; ++j) acc[j] = (f32x4){0.f, 0.f, 0.f, 0.f};

    bf16x8 cw[8];
    #pragma unroll
    for (int s = 0; s < 8; ++s) {
        const float* p = convw + (size_t)(cg * 16 + col) * CC + (kh * 8 + s) * 32 + grp * 8;
        float4 a0 = *(const float4*)p;
        float4 a1 = *(const float4*)(p + 4);
        bf16x8 v;
        v[0] = (short)f2bf(a0.x); v[1] = (short)f2bf(a0.y);
        v[2] = (short)f2bf(a0.z); v[3] = (short)f2bf(a0.w);
        v[4] = (short)f2bf(a1.x); v[5] = (short)f2bf(a1.y);
        v[6] = (short)f2bf(a1.z); v[7] = (short)f2bf(a1.w);
        cw[s] = v;
    }

    const size_t ibase = (size_t)b * (TT * CC);

    float4 r0[2], r1[2];
    #pragma unroll
    for (int i = 0; i < 2; ++i) {
        int g = tid + i * THREADS;
        int t = g >> 6, c8 = (g & 63) << 3;
        const float* p = inp + ibase + (size_t)t * CC + c8;
        r0[i] = *(const float4*)p;
        r1[i] = *(const float4*)(p + 4);
    }

    for (int ch = 0; ch < NCHUNK; ++ch) {
        const int t0 = ch * CHUNK;
        const int tvalid = (TT - t0 < CHUNK) ? (TT - t0) : CHUNK;
        const int buf = ch & 1;
        unsigned short* xb = sm.c.x[buf];

        #pragma unroll
        for (int i = 0; i < 2; ++i) {
            int g = tid + i * THREADS;
            int t = g >> 6, c8 = (g & 63) << 3;
            float4 u0 = r0[i], u1 = r1[i];
            uint4 val = (uint4){pk2cvt(u0.x, u0.y), pk2cvt(u0.z, u0.w),
                                pk2cvt(u1.x, u1.y), pk2cvt(u1.z, u1.w)};
            float s = u0.x*u0.x + u0.y*u0.y + u0.z*u0.z + u0.w*u0.w
                    + u1.x*u1.x + u1.y*u1.y + u1.z*u1.z + u1.w*u1.w;
            if (t >= tvalid) { val = (uint4){0u,0u,0u,0u}; s = 0.f; }
            int off = (t >> 2) * FTBS + (c8 >> 4) * FCBS + (t & 3) * 16 + (c8 & 15);
            *(uint4*)&xb[off] = val;
            sm.c.sumsqP[t][lane] = s;
        }
        if (ch + 1 < NCHUNK) {
            int nt0 = t0 + CHUNK;
            #pragma unroll
            for (int i = 0; i < 2; ++i) {
                int g = tid + i * THREADS;
                int t = g >> 6, c8 = (g & 63) << 3;
                int gt = nt0 + t; if (gt > TT - 1) gt = TT - 1;
                const float* p = inp + ibase + (size_t)gt * CC + c8;
                r0[i] = *(const float4*)p;
                r1[i] = *(const float4*)(p + 4);
            }
        }
        LB();

        {
            f32x4 lt = (f32x4){0.f, 0.f, 0.f, 0.f};
            const int t = th * 16 + col;
            const int rb = (t >> 2) * FTBS + (t & 3) * 16 + ((grp & 1) << 3);
            #pragma unroll
            for (int s = 0; s < 8; ++s) {
                const bf16x8 bb = *(const bf16x8*)&xb[rb + ((kh * 8 + s) * 2 + (grp >> 1)) * FCBS];
                lt = __builtin_amdgcn_mfma_f32_16x16x32_bf16(cw[s], bb, lt, 0, 0, 0);
            }
            #pragma unroll
            for (int r = 0; r < 4; ++r)
                sm.c.logitsP[kh][t][cg * 16 + grp * 4 + r] = lt[r];
        }
        LB();

        if (tid < 512) {
            int t = tid >> 4, part = tid & 15;
            float4 sp = *(const float4*)&sm.c.sumsqP[t][part * 4];
            float ss = sp.x + sp.y + sp.z + sp.w;
            float l[4]; float lmax = -1e30f;
            #pragma unroll
            for (int q = 0; q < 4; ++q) {
                l[q] = sm.c.logitsP[0][t][q * 16 + part] +
                       sm.c.logitsP[1][t][q * 16 + part];
                lmax = fmaxf(lmax, l[q]);
            }
            #pragma unroll
            for (int m = 1; m < 16; m <<= 1) {
                lmax = fmaxf(lmax, __shfl_xor(lmax, m));
                ss  += __shfl_xor(ss, m);
            }
            float rinv = 1.f / fmaxf(sqrtf(ss), 1e-12f);
            rinv = (t < tvalid) ? rinv : 0.f;
            float m0 = lmax * rinv;
            float es = 0.f;
            #pragma unroll
            for (int q = 0; q < 4; ++q) { l[q] = __expf(l[q] * rinv - m0); es += l[q]; }
            #pragma unroll
            for (int m = 1; m < 16; m <<= 1) es += __shfl_xor(es, m);
            float is = 1.f / es;
            #pragma unroll
            for (int q = 0; q < 4; ++q) {
                float a = l[q] * is;
                sm.c.logitsP[0][t][q * 16 + part] = a;
                sm.c.aT[q * 16 + part][t] = (unsigned short)f2bf(a * rinv);
            }
        }
        LB();

        if (tid < KK) {
            float s = 0.f;
            for (int t = 0; t < tvalid; ++t) s += sm.c.logitsP[0][t][tid];
            asum[tid] += s;
        }
        {
            bf16x8 af = *(const bf16x8*)&sm.c.aT[cg * 16 + col][grp * 8];
            unsigned xvb = (unsigned)(uintptr_t)&xb[(grp * 2) * FTBS + (cq * 8) * FCBS + col];
            #pragma unroll
            for (int hh = 0; hh < 2; ++hh) {
                u32x2 lo[4], hi[4];
                #pragma unroll
                for (int j2 = 0; j2 < 4; ++j2) {
                    const unsigned o = (unsigned)((hh * 4 + j2) * 2 * FCBS);
                    asm volatile("ds_read_b64_tr_b16 %0, %1" : "=v"(lo[j2]) : "v"(xvb + o));
                    asm volatile("ds_read_b64_tr_b16 %0, %1" : "=v"(hi[j2]) : "v"(xvb + o + (unsigned)(2 * FTBS)));
                }
                asm volatile("s_waitcnt lgkmcnt(0)" ::: "memory");
                __builtin_amdgcn_sched_barrier(0);
                #pragma unroll
                for (int j2 = 0; j2 < 4; ++j2) {
                    union { bf16x8 v; u32x2 u[2]; } pk;
                    pk.u[0] = lo[j2]; pk.u[1] = hi[j2];
                    acc[hh * 4 + j2] = __builtin_amdgcn_mfma_f32_16x16x32_bf16(
                        af, pk.v, acc[hh * 4 + j2], 0, 0, 0);
                }
            }
        }
    }

    LB();
    #pragma unroll
    for (int r = 0; r < 4; ++r) {
        int cl = cg * 16 + grp * 4 + r;
        float as = asum[cl];
        float ss = 0.f;
        #pragma unroll
        for (int j = 0; j < 8; ++j) {
            int c = cq * 128 + j * 16 + col;
            float v = acc[j][r] - as * cent[(size_t)cl * CC + c];
            acc[j][r] = v;
            ss += v * v;
        }
        ss += __shfl_xor(ss, 1); ss += __shfl_xor(ss, 2);
        ss += __shfl_xor(ss, 4); ss += __shfl_xor(ss, 8);
        if (col == 0) ssred[cq][cl] = ss;
    }
    LB();
    float contrib = 0.f;
    #pragma unroll
    for (int r = 0; r < 4; ++r) {
        int cl = cg * 16 + grp * 4 + r;
        float ss = ssred[0][cl] + ssred[1][cl] + ssred[2][cl] + ssred[3][cl];
        float inv = 1.f / fmaxf(sqrtf(ss), 1e-12f);
        #pragma unroll
        for (int j = 0; j < 8; ++j) {
            float v = acc[j][r] * inv;
            acc[j][r] = v;
            contrib += v * v;
        }
    }
    #pragma unroll
    for (int m = 1; m < 64; m <<= 1) contrib += __shfl_xor(contrib, m);
    if (lane == 0) gred[w] = contrib;
    LB();
    if (tid == 0) {
        float tot = 0.f;
        #pragma unroll
        for (int i = 0; i < 16; ++i) tot += gred[i];
        vinv_sh = 1.f / fmaxf(sqrtf(tot), 1e-12f);
    }
    LB();
    {
        float vinv = vinv_sh;
        #pragma unroll
        for (int r = 0; r < 4; ++r) {
            int cl = cg * 16 + grp * 4 + r;
            #pragma unroll
            for (int j = 0; j < 8; ++j) {
                int c = cq * 128 + j * 16 + col;
                sm.e.vbuf[cl * CC + c] = f2bf(acc[j][r] * vinv);
            }
        }
    }
    LB();
    float pacc[NCLS] = {0.f, 0.f, 0.f, 0.f};
    #pragma unroll
    for (int i = 0; i < 4; ++i) {
        int idx = i * 8192 + tid * 8;
        bf16x8 vv = *(const bf16x8*)&sm.e.vbuf[idx];
        float vf[8];
        #pragma unroll
        for (int h = 0; h < 8; ++h) {
            union { unsigned int u; float f; } cvt;
            cvt.u = ((unsigned int)(unsigned short)vv[h]) << 16;
            vf[h] = cvt.f;
        }
        #pragma unroll
        for (int nc = 0; nc < NCLS; ++nc) {
            const float* wp = fcw + (size_t)nc * (KK * CC) + idx;
            float4 w0 = *(const float4*)wp;
            float4 w1 = *(const float4*)(wp + 4);
            pacc[nc] += vf[0] * w0.x + vf[1] * w0.y + vf[2] * w0.z + vf[3] * w0.w
                      + vf[4] * w1.x + vf[5] * w1.y + vf[6] * w1.z + vf[7] * w1.w;
        }
    }
    #pragma unroll
    for (int nc = 0; nc < NCLS; ++nc) {
        #pragma unroll
        for (int m = 1; m < 64; m <<= 1) pacc[nc] += __shfl_xor(pacc[nc], m);
    }
    if (lane == 0) {
        #pragma unroll
        for (int nc = 0; nc < NCLS; ++nc) fcred[w][nc] = pacc[nc];
    }
    LB();
    if (tid < NCLS) {
        float s = fcb[tid];
        #pragma unroll
        for (int ww = 0; ww < 16; ++ww) s += fcred[ww][tid];
        out[b * NCLS + tid] = 1.f / (1.f + __expf(-s));
    }
}

extern "C" void kernel_launch(void* const* d_in, const int* in_sizes, int n_in,
                              void* d_out, int out_size, void* d_ws, size_t ws_size,
                              hipStream_t stream) {
    const float* inp   = (const float*)d_in[0];
    const float* convw = (const float*)d_in[1];
    const float* cent  = (const float*)d_in[2];
    const float* fcw   = (const float*)d_in[3];
    const float* fcb   = (const float*)d_in[4];
    float* o = (float*)d_out;

    const size_t need = (size_t)512 * KK * CC * 4 + (size_t)512 * KK * 4;
    if (d_ws != nullptr && ws_size >= need) {
        float* wsv = (float*)d_ws;
        float* wsa = wsv + (size_t)512 * KK * CC;
        netvlad_main<<<2 * BB, THREADS, 0, stream>>>(inp, convw, wsv, wsa);
        netvlad_epi<<<BB, THREADS, 0, stream>>>(wsv, wsa, cent, fcw, fcb, o);
    } else {
        netvlad_fallback<<<BB, THREADS, 0, stream>>>(inp, convw, cent, fcw, fcb, o);
    }
}

// Round 3
// 266.061 us; speedup vs baseline: 1.2446x; 1.2446x over previous
//
#include <hip/hip_runtime.h>
#include <hip/hip_bf16.h>
#include <stdint.h>

#define BB 256
#define TT 240
#define CC 512
#define KK 64
#define NCLS 4

// ---------------- main-kernel (split-T) geometry ----------------
#define THREADS 512
#define THALF 120
#define NCH 8           // 7 full chunks of 16 + 1 chunk of 8 per half
#define CHUNK 16
// Subtiled x layout: x[tb][cb][4][16] bf16, tb=t/4 (4 per chunk), cb=c/16 (32)
// CBS=72 elems (144B): c-block bank stride 36 words ≡ 4 mod 32 (conflict-free stage writes)
// TBS=2312 elems: t-block stride 1156 words ≡ 4 mod 32 (conflict-free logits reads)
#define CBS 72
#define TBS 2312
#define XELEMS (4 * TBS)   // 9248 elems = 18,496 B per 16-t buffer

typedef __attribute__((ext_vector_type(8))) short bf16x8;
typedef __attribute__((ext_vector_type(4))) float f32x4;
typedef __attribute__((ext_vector_type(2))) unsigned int u32x2;

__device__ __forceinline__ unsigned short f2bf(float f) {
    union { float f; unsigned int i; } x; x.f = f;
    unsigned int r = x.i + 0x7FFFu + ((x.i >> 16) & 1u);  // RNE, finite only
    return (unsigned short)(r >> 16);
}
__device__ __forceinline__ unsigned int pk2cvt(float lo, float hi) {
    union { __hip_bfloat162 h; unsigned int u; } c;
    c.h = __float22bfloat162_rn(float2{lo, hi});
    return c.u;
}
// LDS-only barrier: doesn't drain vmcnt (global loads stay in flight)
__device__ __forceinline__ void LB() {
    asm volatile("s_waitcnt lgkmcnt(0)\n\ts_barrier" ::: "memory");
}

// ================= kernel 1: main loop (one T-half per block) =================
struct alignas(16) SMem1 {
    unsigned short x[3][XELEMS];    // triple-buffered subtiled x  (55,488 B)
    float logitsP[2][16][67];       // k-half partial logits       ( 8,576 B)
    unsigned short aT[KK][40];      // a' = a*rinv bf16, 2x16t     ( 5,120 B)
    float sumsqP[2][16][16];        // folded sumsq partials       ( 2,048 B)
    float asum[KK];                 // LDS-atomic asum             (   256 B)
};                                  // 71,488 B -> 2 blocks/CU

__device__ __forceinline__ void stage_row(SMem1* sm, float4 u0, float4 u1,
        int t_s, int c8, int lane, int tv, int buf, int slot) {
    uint4 val = (uint4){pk2cvt(u0.x, u0.y), pk2cvt(u0.z, u0.w),
                        pk2cvt(u1.x, u1.y), pk2cvt(u1.z, u1.w)};
    float s = u0.x*u0.x + u0.y*u0.y + u0.z*u0.z + u0.w*u0.w
            + u1.x*u1.x + u1.y*u1.y + u1.z*u1.z + u1.w*u1.w;
    if (t_s >= tv) { val = (uint4){0u,0u,0u,0u}; s = 0.f; }
    int off = (t_s >> 2) * TBS + (c8 >> 4) * CBS + (t_s & 3) * 16 + (c8 & 15);
    *(uint4*)&sm->x[buf][off] = val;
    s += __shfl_xor(s, 16); s += __shfl_xor(s, 32);
    if (lane < 16) sm->sumsqP[slot][t_s][lane] = s;   // 16 partials per row
}

__global__ __launch_bounds__(THREADS, 4) void netvlad_main(
    const float* __restrict__ inp,    // [B,T,C]
    const float* __restrict__ convw,  // [K,C]
    float* __restrict__ wsv,          // [512][K*C] partial vlad
    float* __restrict__ wsa)          // [512][K]   partial asum
{
    __shared__ SMem1 sm;

    const int tid  = threadIdx.x;
    const int blk  = blockIdx.x;
    const int b    = blk >> 1;
    const int half = blk & 1;
    const int w    = tid >> 6;       // wave 0..7
    const int lane = tid & 63;
    const int grp  = (lane >> 4) & 3;
    const int col  = lane & 15;
    const int cg   = w & 3;          // cluster group (logits A / VLAD A)
    const int kh   = w >> 2;         // logits C-half AND VLAD c-half (0..1)

    if (tid < KK) sm.asum[tid] = 0.f;

    f32x4 acc[16];
    #pragma unroll
    for (int j = 0; j < 16; ++j) acc[j] = (f32x4){0.f, 0.f, 0.f, 0.f};

    // conv_w slice: clusters 16cg..+16, C-half kh (8 x bf16x8 = 32 VGPRs)
    bf16x8 cw[8];
    #pragma unroll
    for (int s = 0; s < 8; ++s) {
        const float* p = convw + (size_t)(cg * 16 + col) * CC + (kh * 8 + s) * 32 + grp * 8;
        float4 a0 = *(const float4*)p;
        float4 a1 = *(const float4*)(p + 4);
        bf16x8 v;
        v[0] = (short)f2bf(a0.x); v[1] = (short)f2bf(a0.y);
        v[2] = (short)f2bf(a0.z); v[3] = (short)f2bf(a0.w);
        v[4] = (short)f2bf(a1.x); v[5] = (short)f2bf(a1.y);
        v[6] = (short)f2bf(a1.z); v[7] = (short)f2bf(a1.w);
        cw[s] = v;
    }

    const size_t ibase = (size_t)b * (TT * CC);
    const int tbase = half * THALF;
    const int c8 = lane << 3;        // staging col (8 floats)

    // prologue: stage chunk 0 (rows w and w+8)
    {
        const float* p0 = inp + ibase + (size_t)(tbase + w) * CC + c8;
        const float* p1 = inp + ibase + (size_t)(tbase + w + 8) * CC + c8;
        float4 a0 = *(const float4*)p0, a1 = *(const float4*)(p0 + 4);
        float4 b0 = *(const float4*)p1, b1 = *(const float4*)(p1 + 4);
        stage_row(&sm, a0, a1, w, c8, lane, 16, 0, 0);
        stage_row(&sm, b0, b1, w + 8, c8, lane, 16, 0, 0);
    }
    LB();

    int bufc = 0;
    for (int ch = 0; ch < NCH; ++ch) {
        int bufn = bufc + 1; if (bufn == 3) bufn = 0;
        const int tv = (THALF - ch * CHUNK > CHUNK) ? CHUNK : (THALF - ch * CHUNK);
        const bool do_stage = (ch + 1 < NCH);

        // ---- P1: issue next-chunk loads, logits(ch), stage(ch+1) ----
        float4 u0a, u1a, u0b, u1b;
        if (do_stage) {
            int tg0 = tbase + (ch + 1) * CHUNK + w;
            int tg1 = tg0 + 8; if (tg1 > TT - 1) tg1 = TT - 1;  // clamp addr only
            const float* p0 = inp + ibase + (size_t)tg0 * CC + c8;
            const float* p1 = inp + ibase + (size_t)tg1 * CC + c8;
            u0a = *(const float4*)p0; u1a = *(const float4*)(p0 + 4);
            u0b = *(const float4*)p1; u1b = *(const float4*)(p1 + 4);
        }
        {
            const unsigned short* xb = sm.x[bufc];
            f32x4 lt = (f32x4){0.f, 0.f, 0.f, 0.f};
            const int rb = (col >> 2) * TBS + (col & 3) * 16 + (grp & 1) * 8;
            #pragma unroll
            for (int s = 0; s < 8; ++s) {
                const bf16x8 bb = *(const bf16x8*)&xb[rb + ((kh * 8 + s) * 2 + (grp >> 1)) * CBS];
                lt = __builtin_amdgcn_mfma_f32_16x16x32_bf16(cw[s], bb, lt, 0, 0, 0);
            }
            #pragma unroll
            for (int r = 0; r < 4; ++r)
                sm.logitsP[kh][col][cg * 16 + grp * 4 + r] = lt[r];
        }
        if (do_stage) {
            int tvn = THALF - (ch + 1) * CHUNK; if (tvn > CHUNK) tvn = CHUNK;
            stage_row(&sm, u0a, u1a, w, c8, lane, tvn, bufn, (ch + 1) & 1);
            stage_row(&sm, u0b, u1b, w + 8, c8, lane, tvn, bufn, (ch + 1) & 1);
        }
        LB();  // logitsP(ch) + x(ch+1) + sumsq(ch+1) ready

        // ---- P2: sumsq finish + softmax + asum (tid<256, waves 0-3) ----
        if (tid < 256) {
            int t = tid >> 4, part = tid & 15;
            float ss = sm.sumsqP[ch & 1][t][part];
            float l[4]; float lmax = -1e30f;
            #pragma unroll
            for (int q = 0; q < 4; ++q) {
                int c = q * 16 + part;
                l[q] = sm.logitsP[0][t][c] + sm.logitsP[1][t][c];
                lmax = fmaxf(lmax, l[q]);
            }
            #pragma unroll
            for (int m = 1; m < 16; m <<= 1) {
                lmax = fmaxf(lmax, __shfl_xor(lmax, m));
                ss  += __shfl_xor(ss, m);
            }
            float rinv = 1.f / fmaxf(sqrtf(ss), 1e-12f);
            rinv = (t < tv) ? rinv : 0.f;
            float m0 = lmax * rinv;
            float es = 0.f;
            #pragma unroll
            for (int q = 0; q < 4; ++q) { l[q] = __expf(l[q] * rinv - m0); es += l[q]; }
            #pragma unroll
            for (int m = 1; m < 16; m <<= 1) es += __shfl_xor(es, m);
            float is = 1.f / es;
            int tofs = (ch & 1) * 16;
            float am[4];
            #pragma unroll
            for (int q = 0; q < 4; ++q) {
                float a = l[q] * is;
                sm.aT[q * 16 + part][tofs + t] = (unsigned short)f2bf(a * rinv); // 0 if masked
                am[q] = (t < tv) ? a : 0.f;
            }
            #pragma unroll
            for (int q = 0; q < 4; ++q) { am[q] += __shfl_xor(am[q], 16); am[q] += __shfl_xor(am[q], 32); }
            if (lane < 16) {
                #pragma unroll
                for (int q = 0; q < 4; ++q) atomicAdd(&sm.asum[q * 16 + lane], am[q]);
            }
        }
        LB();  // aT slot (ch&1) ready

        // ---- P3 (odd ch): VLAD over the pair (K=32) via HW transpose reads ----
        if (ch & 1) {
            bf16x8 af = *(const bf16x8*)&sm.aT[cg * 16 + col][grp * 8];
            int bufE = bufc + 2; if (bufE >= 3) bufE -= 3;   // (ch-1)%3
            // grp 0,1 -> even-chunk buffer; grp 2,3 -> odd (current)
            unsigned bsel = (grp >> 1) ? (unsigned)bufc : (unsigned)bufE;
            unsigned base = (unsigned)(uintptr_t)&sm.x[0][0]
                + (bsel * (unsigned)XELEMS
                   + (unsigned)(((grp & 1) * 2) * TBS + (kh * 16) * CBS + col)) * 2u;
            #pragma unroll
            for (int q4 = 0; q4 < 4; ++q4) {
                u32x2 lo[4], hi[4];
                #pragma unroll
                for (int j2 = 0; j2 < 4; ++j2) {
                    unsigned o = base + (unsigned)((q4 * 4 + j2) * (2 * CBS));
                    asm volatile("ds_read_b64_tr_b16 %0, %1" : "=v"(lo[j2]) : "v"(o));
                    asm volatile("ds_read_b64_tr_b16 %0, %1" : "=v"(hi[j2]) : "v"(o + (unsigned)(2 * TBS)));
                }
                asm volatile("s_waitcnt lgkmcnt(0)" ::: "memory");
                __builtin_amdgcn_sched_barrier(0);
                #pragma unroll
                for (int j2 = 0; j2 < 4; ++j2) {
                    union { bf16x8 v; u32x2 u[2]; } pk;
                    pk.u[0] = lo[j2]; pk.u[1] = hi[j2];
                    acc[q4 * 4 + j2] = __builtin_amdgcn_mfma_f32_16x16x32_bf16(
                        af, pk.v, acc[q4 * 4 + j2], 0, 0, 0);
                }
            }
            LB();  // protect x bufs + aT before reuse
        }
        bufc = bufn;
    }

    // ---- write partials ----
    if (tid < KK) wsa[blk * KK + tid] = sm.asum[tid];
    float* wv = wsv + (size_t)blk * (KK * CC);
    #pragma unroll
    for (int r = 0; r < 4; ++r) {
        int cl = cg * 16 + grp * 4 + r;
        #pragma unroll
        for (int j = 0; j < 16; ++j)
            wv[cl * CC + kh * 256 + j * 16 + col] = acc[j][r];
    }
}

// ================= kernel 2: combine + normalize + FC =================
struct alignas(16) SMem2 {
    unsigned short vbuf[KK][520];   // padded rows (66,560 B)
    float gred[16];
    float fcred[16][NCLS];
    float vinv;
};

__global__ __launch_bounds__(1024) void netvlad_epi(
    const float* __restrict__ wsv, const float* __restrict__ wsa,
    const float* __restrict__ cent, const float* __restrict__ fcw,
    const float* __restrict__ fcb, float* __restrict__ out)
{
    __shared__ SMem2 sm;
    const int tid = threadIdx.x, b = blockIdx.x;
    const int w = tid >> 6, lane = tid & 63;
    const int cl = tid >> 4, part = tid & 15, c0 = part * 32;

    const float* v0 = wsv + (size_t)(2 * b) * (KK * CC) + (size_t)cl * CC + c0;
    const float* v1 = v0 + KK * CC;
    const float* cp = cent + (size_t)cl * CC + c0;
    float as = wsa[(2 * b) * KK + cl] + wsa[(2 * b + 1) * KK + cl];

    float v[32]; float ss = 0.f;
    #pragma unroll
    for (int i = 0; i < 8; ++i) {
        float4 a  = *(const float4*)(v0 + 4 * i);
        float4 bq = *(const float4*)(v1 + 4 * i);
        float4 c4 = *(const float4*)(cp + 4 * i);
        float x0 = a.x + bq.x - as * c4.x;
        float x1 = a.y + bq.y - as * c4.y;
        float x2 = a.z + bq.z - as * c4.z;
        float x3 = a.w + bq.w - as * c4.w;
        v[4*i] = x0; v[4*i+1] = x1; v[4*i+2] = x2; v[4*i+3] = x3;
        ss += x0*x0 + x1*x1 + x2*x2 + x3*x3;
    }
    #pragma unroll
    for (int m = 1; m < 16; m <<= 1) ss += __shfl_xor(ss, m);
    float inv = 1.f / fmaxf(sqrtf(ss), 1e-12f);
    float contrib = 0.f;
    #pragma unroll
    for (int i = 0; i < 32; ++i) { v[i] *= inv; contrib += v[i] * v[i]; }
    #pragma unroll
    for (int m = 1; m < 64; m <<= 1) contrib += __shfl_xor(contrib, m);
    if (lane == 0) sm.gred[w] = contrib;
    __syncthreads();
    if (tid == 0) {
        float tot = 0.f;
        #pragma unroll
        for (int i = 0; i < 16; ++i) tot += sm.gred[i];
        sm.vinv = 1.f / fmaxf(sqrtf(tot), 1e-12f);
    }
    __syncthreads();
    {
        float vinv = sm.vinv;
        #pragma unroll
        for (int i = 0; i < 4; ++i) {
            uint4 pv = (uint4){ pk2cvt(v[8*i]*vinv,   v[8*i+1]*vinv),
                                pk2cvt(v[8*i+2]*vinv, v[8*i+3]*vinv),
                                pk2cvt(v[8*i+4]*vinv, v[8*i+5]*vinv),
                                pk2cvt(v[8*i+6]*vinv, v[8*i+7]*vinv) };
            *(uint4*)&sm.vbuf[cl][c0 + 8 * i] = pv;
        }
    }
    __syncthreads();

    float pacc[NCLS] = {0.f, 0.f, 0.f, 0.f};
    #pragma unroll
    for (int i = 0; i < 4; ++i) {
        int idx = i * 8192 + tid * 8;
        int row = idx >> 9, off = idx & 511;
        bf16x8 vv = *(const bf16x8*)&sm.vbuf[row][off];
        float vf[8];
        #pragma unroll
        for (int h = 0; h < 8; ++h) {
            union { unsigned int u; float f; } cvt;
            cvt.u = ((unsigned int)(unsigned short)vv[h]) << 16;
            vf[h] = cvt.f;
        }
        #pragma unroll
        for (int nc = 0; nc < NCLS; ++nc) {
            const float* wp = fcw + (size_t)nc * (KK * CC) + idx;
            float4 w0 = *(const float4*)wp;
            float4 w1 = *(const float4*)(wp + 4);
            pacc[nc] += vf[0]*w0.x + vf[1]*w0.y + vf[2]*w0.z + vf[3]*w0.w
                      + vf[4]*w1.x + vf[5]*w1.y + vf[6]*w1.z + vf[7]*w1.w;
        }
    }
    #pragma unroll
    for (int nc = 0; nc < NCLS; ++nc) {
        #pragma unroll
        for (int m = 1; m < 64; m <<= 1) pacc[nc] += __shfl_xor(pacc[nc], m);
    }
    if (lane == 0) {
        #pragma unroll
        for (int nc = 0; nc < NCLS; ++nc) sm.fcred[w][nc] = pacc[nc];
    }
    __syncthreads();
    if (tid < NCLS) {
        float s = fcb[tid];
        #pragma unroll
        for (int ww = 0; ww < 16; ++ww) s += sm.fcred[ww][tid];
        out[b * NCLS + tid] = 1.f / (1.f + __expf(-s));
    }
}

// ================= fallback: R1 verified single kernel =================
#define FCHUNK 32
#define FNCHUNK 8
#define FCBS 72
#define FTBS 2312
#define FXELEMS (8 * FTBS)

struct alignas(16) SMemChunkF {
    unsigned short x[2][FXELEMS];
    float logitsP[2][FCHUNK][67];
    unsigned short aT[KK][40];
    float sumsqP[FCHUNK][68];
};
struct alignas(16) SMemEpiF { unsigned short vbuf[KK * CC]; };
union SMemUF { SMemChunkF c; SMemEpiF e; };

__global__ __launch_bounds__(1024, 4) void netvlad_fallback(
    const float* __restrict__ inp, const float* __restrict__ convw,
    const float* __restrict__ cent, const float* __restrict__ fcw,
    const float* __restrict__ fcb, float* __restrict__ out)
{
    __shared__ SMemUF sm;
    __shared__ float asum[KK];
    __shared__ float ssred[4][KK];
    __shared__ float gred[16];
    __shared__ float fcred[16][NCLS];
    __shared__ float vinv_sh;

    const int tid  = threadIdx.x;
    const int b    = blockIdx.x;
    const int w    = tid >> 6;
    const int lane = tid & 63;
    const int grp  = (lane >> 4) & 3;
    const int col  = lane & 15;
    const int cg   = w & 3;
    const int th   = (w >> 2) & 1;
    const int kh   = w >> 3;
    const int cq   = w >> 2;

    if (tid < KK) asum[tid] = 0.f;

    f32x4 acc[8];
    #pragma unroll
    for (int j = 0; j < 8; ++j) acc[j] = (f32x4){0.f, 0.f, 0.f, 0.f};

    bf16x8 cw[8];
    #pragma unroll
    for (int s = 0; s < 8; ++s) {
        const float* p = convw + (size_t)(cg * 16 + col) * CC + (kh * 8 + s) * 32 + grp * 8;
        float4 a0 = *(const float4*)p;
        float4 a1 = *(const float4*)(p + 4);
        bf16x8 v;
        v[0] = (short)f2bf(a0.x); v[1] = (short)f2bf(a0.y);
        v[2] = (short)f2bf(a0.z); v[3] = (short)f2bf(a0.w);
        v[4] = (short)f2bf(a1.x); v[5] = (short)f2bf(a1.y);
        v[6] = (short)f2bf(a1.z); v[7] = (short)f2bf(a1.w);
        cw[s] = v;
    }

    const size_t ibase = (size_t)b * (TT * CC);

    float4 r0[2], r1[2];
    #pragma unroll
    for (int i = 0; i < 2; ++i) {
        int g = tid + i * 1024;
        int t = g >> 6, c8 = (g & 63) << 3;
        const float* p = inp + ibase + (size_t)t * CC + c8;
        r0[i] = *(const float4*)p;
        r1[i] = *(const float4*)(p + 4);
    }

    for (int ch = 0; ch < FNCHUNK; ++ch) {
        const int t0 = ch * FCHUNK;
        const int tvalid = (TT - t0 < FCHUNK) ? (TT - t0) : FCHUNK;
        const int buf = ch & 1;
        unsigned short* xb = sm.c.x[buf];

        #pragma unroll
        for (int i = 0; i < 2; ++i) {
            int g = tid + i * 1024;
            int t = g >> 6, c8 = (g & 63) << 3;
            float4 u0 = r0[i], u1 = r1[i];
            uint4 val = (uint4){pk2cvt(u0.x, u0.y), pk2cvt(u0.z, u0.w),
                                pk2cvt(u1.x, u1.y), pk2cvt(u1.z, u1.w)};
            float s = u0.x*u0.x + u0.y*u0.y + u0.z*u0.z + u0.w*u0.w
                    + u1.x*u1.x + u1.y*u1.y + u1.z*u1.z + u1.w*u1.w;
            if (t >= tvalid) { val = (uint4){0u,0u,0u,0u}; s = 0.f; }
            int off = (t >> 2) * FTBS + (c8 >> 4) * FCBS + (t & 3) * 16 + (c8 & 15);
            *(uint4*)&xb[off] = val;
            sm.c.sumsqP[t][lane] = s;
        }
        if (ch + 1 < FNCHUNK) {
            int nt0 = t0 + FCHUNK;
            #pragma unroll
            for (int i = 0; i < 2; ++i) {
                int g = tid + i * 1024;
                int t = g >> 6, c8 = (g & 63) << 3;
                int gt = nt0 + t; if (gt > TT - 1) gt = TT - 1;
                const float* p = inp + ibase + (size_t)gt * CC + c8;
                r0[i] = *(const float4*)p;
                r1[i] = *(const float4*)(p + 4);
            }
        }
        LB();

        {
            f32x4 lt = (f32x4){0.f, 0.f, 0.f, 0.f};
            const int t = th * 16 + col;
            const int rb = (t >> 2) * FTBS + (t & 3) * 16 + ((grp & 1) << 3);
            #pragma unroll
            for (int s = 0; s < 8; ++s) {
                const bf16x8 bb = *(const bf16x8*)&xb[rb + ((kh * 8 + s) * 2 + (grp >> 1)) * FCBS];
                lt = __builtin_amdgcn_mfma_f32_16x16x32_bf16(cw[s], bb, lt, 0, 0, 0);
            }
            #pragma unroll
            for (int r = 0; r < 4; ++r)
                sm.c.logitsP[kh][t][cg * 16 + grp * 4 + r] = lt[r];
        }
        LB();

        if (tid < 512) {
            int t = tid >> 4, part = tid & 15;
            float4 sp = *(const float4*)&sm.c.sumsqP[t][part * 4];
            float ss = sp.x + sp.y + sp.z + sp.w;
            float l[4]; float lmax = -1e30f;
            #pragma unroll
            for (int q = 0; q < 4; ++q) {
                l[q] = sm.c.logitsP[0][t][q * 16 + part] +
                       sm.c.logitsP[1][t][q * 16 + part];
                lmax = fmaxf(lmax, l[q]);
            }
            #pragma unroll
            for (int m = 1; m < 16; m <<= 1) {
                lmax = fmaxf(lmax, __shfl_xor(lmax, m));
                ss  += __shfl_xor(ss, m);
            }
            float rinv = 1.f / fmaxf(sqrtf(ss), 1e-12f);
            rinv = (t < tvalid) ? rinv : 0.f;
            float m0 = lmax * rinv;
            float es = 0.f;
            #pragma unroll
            for (int q = 0; q < 4; ++q) { l[q] = __expf(l[q] * rinv - m0); es += l[q]; }
            #pragma unroll
            for (int m = 1; m < 16; m <<= 1) es += __shfl_xor(es, m);
            float is = 1.f / es;
            #pragma unroll
            for (int q = 0; q < 4; ++q) {
                float a = l[q] * is;
                sm.c.logitsP[0][t][q * 16 + part] = a;
                sm.c.aT[q * 16 + part][t] = (unsigned short)f2bf(a * rinv);
            }
        }
        LB();

        if (tid < KK) {
            float s = 0.f;
            for (int t = 0; t < tvalid; ++t) s += sm.c.logitsP[0][t][tid];
            asum[tid] += s;
        }
        {
            bf16x8 af = *(const bf16x8*)&sm.c.aT[cg * 16 + col][grp * 8];
            unsigned xvb = (unsigned)(uintptr_t)&xb[(grp * 2) * FTBS + (cq * 8) * FCBS + col];
            #pragma unroll
            for (int hh = 0; hh < 2; ++hh) {
                u32x2 lo[4], hi[4];
                #pragma unroll
                for (int j2 = 0; j2 < 4; ++j2) {
                    const unsigned o = (unsigned)((hh * 4 + j2) * 2 * FCBS);
                    asm volatile("ds_read_b64_tr_b16 %0, %1" : "=v"(lo[j2]) : "v"(xvb + o));
                    asm volatile("ds_read_b64_tr_b16 %0, %1" : "=v"(hi[j2]) : "v"(xvb + o + (unsigned)(2 * FTBS)));
                }
                asm volatile("s_waitcnt lgkmcnt(0)" ::: "memory");
                __builtin_amdgcn_sched_barrier(0);
                #pragma unroll
                for (int j2 = 0; j2 < 4; ++j2) {
                    union { bf16x8 v; u32x2 u[2]; } pk;
                    pk.u[0] = lo[j2]; pk.u[1] = hi[j2];
                    acc[hh * 4 + j2] = __builtin_amdgcn_mfma_f32_16x16x32_bf16(
                        af, pk.v, acc[hh * 4 + j2], 0, 0, 0);
                }
            }
        }
    }

    LB();
    #pragma unroll
    for (int r = 0; r < 4; ++r) {
        int cl = cg * 16 + grp * 4 + r;
        float as = asum[cl];
        float ss = 0.f;
        #pragma unroll
        for (int j = 0; j < 8; ++j) {
            int c = cq * 128 + j * 16 + col;
            float v = acc[j][r] - as * cent[(size_t)cl * CC + c];
            acc[j][r] = v;
            ss += v * v;
        }
        ss += __shfl_xor(ss, 1); ss += __shfl_xor(ss, 2);
        ss += __shfl_xor(ss, 4); ss += __shfl_xor(ss, 8);
        if (col == 0) ssred[cq][cl] = ss;
    }
    LB();
    float contrib = 0.f;
    #pragma unroll
    for (int r = 0; r < 4; ++r) {
        int cl = cg * 16 + grp * 4 + r;
        float ss = ssred[0][cl] + ssred[1][cl] + ssred[2][cl] + ssred[3][cl];
        float inv = 1.f / fmaxf(sqrtf(ss), 1e-12f);
        #pragma unroll
        for (int j = 0; j < 8; ++j) {
            float v = acc[j][r] * inv;
            acc[j][r] = v;
            contrib += v * v;
        }
    }
    #pragma unroll
    for (int m = 1; m < 64; m <<= 1) contrib += __shfl_xor(contrib, m);
    if (lane == 0) gred[w] = contrib;
    LB();
    if (tid == 0) {
        float tot = 0.f;
        #pragma unroll
        for (int i = 0; i < 16; ++i) tot += gred[i];
        vinv_sh = 1.f / fmaxf(sqrtf(tot), 1e-12f);
    }
    LB();
    {
        float vinv = vinv_sh;
        #pragma unroll
        for (int r = 0; r < 4; ++r) {
            int cl = cg * 16 + grp * 4 + r;
            #pragma unroll
            for (int j = 0; j < 8; ++j) {
                int c = cq * 128 + j * 16 + col;
                sm.e.vbuf[cl * CC + c] = f2bf(acc[j][r] * vinv);
            }
        }
    }
    LB();
    float pacc[NCLS] = {0.f, 0.f, 0.f, 0.f};
    #pragma unroll
    for (int i = 0; i < 4; ++i) {
        int idx = i * 8192 + tid * 8;
        bf16x8 vv = *(const bf16x8*)&sm.e.vbuf[idx];
        float vf[8];
        #pragma unroll
        for (int h = 0; h < 8; ++h) {
            union { unsigned int u; float f; } cvt;
            cvt.u = ((unsigned int)(unsigned short)vv[h]) << 16;
            vf[h] = cvt.f;
        }
        #pragma unroll
        for (int nc = 0; nc < NCLS; ++nc) {
            const float* wp = fcw + (size_t)nc * (KK * CC) + idx;
            float4 w0 = *(const float4*)wp;
            float4 w1 = *(const float4*)(wp + 4);
            pacc[nc] += vf[0] * w0.x + vf[1] * w0.y + vf[2] * w0.z + vf[3] * w0.w
                      + vf[4] * w1.x + vf[5] * w1.y + vf[6] * w1.z + vf[7] * w1.w;
        }
    }
    #pragma unroll
    for (int nc = 0; nc < NCLS; ++nc) {
        #pragma unroll
        for (int m = 1; m < 64; m <<= 1) pacc[nc] += __shfl_xor(pacc[nc], m);
    }
    if (lane == 0) {
        #pragma unroll
        for (int nc = 0; nc < NCLS; ++nc) fcred[w][nc] = pacc[nc];
    }
    LB();
    if (tid < NCLS) {
        float s = fcb[tid];
        #pragma unroll
        for (int ww = 0; ww < 16; ++ww) s += fcred[ww][tid];
        out[b * NCLS + tid] = 1.f / (1.f + __expf(-s));
    }
}

extern "C" void kernel_launch(void* const* d_in, const int* in_sizes, int n_in,
                              void* d_out, int out_size, void* d_ws, size_t ws_size,
                              hipStream_t stream) {
    const float* inp   = (const float*)d_in[0];
    const float* convw = (const float*)d_in[1];
    const float* cent  = (const float*)d_in[2];
    const float* fcw   = (const float*)d_in[3];
    const float* fcb   = (const float*)d_in[4];
    float* o = (float*)d_out;

    const size_t need = (size_t)512 * KK * CC * 4 + (size_t)512 * KK * 4;
    if (d_ws != nullptr && ws_size >= need) {
        float* wsv = (float*)d_ws;
        float* wsa = wsv + (size_t)512 * KK * CC;
        netvlad_main<<<2 * BB, THREADS, 0, stream>>>(inp, convw, wsv, wsa);
        netvlad_epi<<<BB, 1024, 0, stream>>>(wsv, wsa, cent, fcw, fcb, o);
    } else {
        netvlad_fallback<<<BB, 1024, 0, stream>>>(inp, convw, cent, fcw, fcb, o);
    }
}

// Round 5
// 230.718 us; speedup vs baseline: 1.4353x; 1.1532x over previous
//
#include <hip/hip_runtime.h>
#include <hip/hip_bf16.h>
#include <stdint.h>

#define BB 256
#define TT 240
#define CC 512
#define KK 64
#define NCLS 4
#define CHUNK 32
#define NCH 8          // 7 full chunks + 1 half (tvalid=16)
#define THREADS 1024

// Subtiled x layout: x[tb][cb][4][16] bf16, tb=t/4 (8 per chunk), cb=c/16 (32)
// CBS=72 elems (144 B): c-block bank stride 36 words == 4 mod 32 (verified R1)
// TBS=2312 elems (4624 B): t-block stride == 4 mod 32 (verified R1)
#define CBS 72
#define TBS 2312
#define XELEMS (8 * TBS)   // 18,496 elems = 36,992 B per 32-t buffer

typedef __attribute__((ext_vector_type(8))) short bf16x8;
typedef __attribute__((ext_vector_type(4))) float f32x4;
typedef __attribute__((ext_vector_type(2))) unsigned int u32x2;

__device__ __forceinline__ unsigned short f2bf(float f) {
    union { float f; unsigned int i; } x; x.f = f;
    unsigned int r = x.i + 0x7FFFu + ((x.i >> 16) & 1u);  // RNE, finite only
    return (unsigned short)(r >> 16);
}
__device__ __forceinline__ unsigned int pk2cvt(float lo, float hi) {
    union { __hip_bfloat162 h; unsigned int u; } c;
    c.h = __float22bfloat162_rn(float2{lo, hi});
    return c.u;
}
// LDS-only barrier: doesn't drain vmcnt (global prefetch stays in flight)
__device__ __forceinline__ void LB() {
    asm volatile("s_waitcnt lgkmcnt(0)\n\ts_barrier" ::: "memory");
}

struct alignas(16) SMemChunk {
    unsigned short x[3][XELEMS];    // triple-buffered subtiled x  (110,976 B)
    float logitsP[2][CHUNK][67];    // k-half partial logits       ( 17,152 B)
    unsigned short aT[2][KK][40];   // a' = a*rinv bf16, 2 slots   ( 10,240 B)
    float sumsqP[2][CHUNK][16];     // folded sumsq partials       (  4,096 B)
    float asumP[16][KK];            // per-wave asum accumulators  (  4,096 B)
};                                  // 146,560 B
struct alignas(16) SMemEpi { unsigned short vbuf[KK * CC]; };  // 64 KB
union SMemU { SMemChunk c; SMemEpi e; };

__device__ __forceinline__ void stage_row(unsigned short* xb, float* ssp,
        float4 u0, float4 u1, int t, int c8, int lane, int tv) {
    uint4 val = (uint4){pk2cvt(u0.x, u0.y), pk2cvt(u0.z, u0.w),
                        pk2cvt(u1.x, u1.y), pk2cvt(u1.z, u1.w)};
    float s = u0.x*u0.x + u0.y*u0.y + u0.z*u0.z + u0.w*u0.w
            + u1.x*u1.x + u1.y*u1.y + u1.z*u1.z + u1.w*u1.w;
    if (t >= tv) { val = (uint4){0u,0u,0u,0u}; s = 0.f; }
    int off = (t >> 2) * TBS + (c8 >> 4) * CBS + (t & 3) * 16 + (c8 & 15);
    *(uint4*)&xb[off] = val;
    s += __shfl_xor(s, 16); s += __shfl_xor(s, 32);
    if (lane < 16) ssp[t * 16 + lane] = s;   // 16 partials per row
}

__global__ __launch_bounds__(THREADS, 4) void netvlad_kernel(
    const float* __restrict__ inp,    // [B,T,C]
    const float* __restrict__ convw,  // [K,C]
    const float* __restrict__ cent,   // [K,C]
    const float* __restrict__ fcw,    // [NC, K*C]
    const float* __restrict__ fcb,    // [NC]
    float* __restrict__ out)          // [B,NC]
{
    __shared__ SMemU sm;
    __shared__ float asumF[KK];
    __shared__ float ssred[4][KK];
    __shared__ float gred[16];
    __shared__ float fcred[16][NCLS];
    __shared__ float vinv_sh;

    const int tid  = threadIdx.x;
    const int b    = blockIdx.x;
    const int w    = tid >> 6;       // wave 0..15
    const int lane = tid & 63;
    const int grp  = (lane >> 4) & 3;
    const int col  = lane & 15;
    const int cg   = w & 3;          // cluster group (logits/VLAD/epilogue)
    const int th   = (w >> 2) & 1;   // logits t-tile
    const int kh   = w >> 3;         // logits k-half
    const int cq   = w >> 2;         // VLAD c-quarter

    ((float*)sm.c.asumP)[tid] = 0.f;   // 16*64 = 1024 entries

    f32x4 acc[8];
    #pragma unroll
    for (int j = 0; j < 8; ++j) acc[j] = (f32x4){0.f, 0.f, 0.f, 0.f};

    const size_t ibase = (size_t)b * (TT * CC);
    const int c8 = lane << 3;

#define ISSUE(pr, nc) do { \
        int tg0_ = (nc) * CHUNK + w;      if (tg0_ > TT - 1) tg0_ = TT - 1; \
        int tg1_ = (nc) * CHUNK + w + 16; if (tg1_ > TT - 1) tg1_ = TT - 1; \
        const float* p0_ = inp + ibase + (size_t)tg0_ * CC + c8; \
        const float* p1_ = inp + ibase + (size_t)tg1_ * CC + c8; \
        pr[0] = *(const float4*)p0_; pr[1] = *(const float4*)(p0_ + 4); \
        pr[2] = *(const float4*)p1_; pr[3] = *(const float4*)(p1_ + 4); \
    } while (0)

#define STAGE(pr, nc) do { \
        const int tv_ = (TT - (nc) * CHUNK < CHUNK) ? (TT - (nc) * CHUNK) : CHUNK; \
        unsigned short* xb_ = sm.c.x[(nc) % 3]; \
        float* ssp_ = &sm.c.sumsqP[(nc) & 1][0][0]; \
        stage_row(xb_, ssp_, pr[0], pr[1], w,      c8, lane, tv_); \
        stage_row(xb_, ssp_, pr[2], pr[3], w + 16, c8, lane, tv_); \
    } while (0)

    // ---- prologue: stage chunk 0 via preB; issue chunks 1,2 ----
    float4 preA[4], preB[4];     // preA = odd chunks, preB = even
    ISSUE(preB, 0);

    // conv_w slice: clusters 16cg..+16, k-half kh (8 x bf16x8 = 32 VGPRs)
    bf16x8 cw[8];
    #pragma unroll
    for (int s = 0; s < 8; ++s) {
        const float* p = convw + (size_t)(cg * 16 + col) * CC + (kh * 8 + s) * 32 + grp * 8;
        float4 a0 = *(const float4*)p;
        float4 a1 = *(const float4*)(p + 4);
        bf16x8 v;
        v[0] = (short)f2bf(a0.x); v[1] = (short)f2bf(a0.y);
        v[2] = (short)f2bf(a0.z); v[3] = (short)f2bf(a0.w);
        v[4] = (short)f2bf(a1.x); v[5] = (short)f2bf(a1.y);
        v[6] = (short)f2bf(a1.z); v[7] = (short)f2bf(a1.w);
        cw[s] = v;
    }

    STAGE(preB, 0);
    ISSUE(preA, 1);
    ISSUE(preB, 2);
    LB();

    for (int ch = 0; ch < NCH; ++ch) {
        // ---- P1: stage(ch+1) + logits(ch) ----
        if (ch + 1 < NCH) {
            if (((ch + 1) & 1) == 1) STAGE(preA, ch + 1);
            else                     STAGE(preB, ch + 1);
        }
        {
            const unsigned short* xb = sm.c.x[ch % 3];
            f32x4 lt = (f32x4){0.f, 0.f, 0.f, 0.f};
            const int t = th * 16 + col;
            const int rb = (t >> 2) * TBS + (t & 3) * 16 + ((grp & 1) << 3);
            #pragma unroll
            for (int s = 0; s < 8; ++s) {
                const bf16x8 bb = *(const bf16x8*)&xb[rb + ((kh * 8 + s) * 2 + (grp >> 1)) * CBS];
                lt = __builtin_amdgcn_mfma_f32_16x16x32_bf16(cw[s], bb, lt, 0, 0, 0);
            }
            #pragma unroll
            for (int r = 0; r < 4; ++r)
                sm.c.logitsP[kh][t][cg * 16 + grp * 4 + r] = lt[r];
        }
        LB();  // logitsP(ch) + x(ch+1) + sumsq(ch+1) ready

        // ---- P2: issue(ch+3) + softmax(ch) [all 16 waves] + VLAD(ch-1) ----
        if (ch + 3 < NCH) {
            if (((ch + 3) & 1) == 1) ISSUE(preA, ch + 3);
            else                     ISSUE(preB, ch + 3);
        }
        {
            const int tv = (TT - ch * CHUNK < CHUNK) ? (TT - ch * CHUNK) : CHUNK;
            const int t = tid >> 5;        // 0..31 (32 threads per row)
            const int p32 = lane & 31;     // clusters p32 and 32+p32
            float ss = (p32 < 16) ? sm.c.sumsqP[ch & 1][t][p32] : 0.f;
            float l0 = sm.c.logitsP[0][t][p32]      + sm.c.logitsP[1][t][p32];
            float l1 = sm.c.logitsP[0][t][32 + p32] + sm.c.logitsP[1][t][32 + p32];
            float lmax = fmaxf(l0, l1);
            #pragma unroll
            for (int m = 1; m < 32; m <<= 1) {
                lmax = fmaxf(lmax, __shfl_xor(lmax, m));
                ss  += __shfl_xor(ss, m);
            }
            float rinv = 1.f / fmaxf(sqrtf(ss), 1e-12f);
            rinv = (t < tv) ? rinv : 0.f;
            float m0 = lmax * rinv;
            l0 = __expf(l0 * rinv - m0);
            l1 = __expf(l1 * rinv - m0);
            float es = l0 + l1;
            #pragma unroll
            for (int m = 1; m < 32; m <<= 1) es += __shfl_xor(es, m);
            float is = 1.f / es;
            float a0 = l0 * is, a1 = l1 * is;
            sm.c.aT[ch & 1][p32][t]      = (unsigned short)f2bf(a0 * rinv);  // 0 if masked
            sm.c.aT[ch & 1][32 + p32][t] = (unsigned short)f2bf(a1 * rinv);
            float am0 = (t < tv) ? a0 : 0.f;
            float am1 = (t < tv) ? a1 : 0.f;
            am0 += __shfl_xor(am0, 32);
            am1 += __shfl_xor(am1, 32);
            if (lane < 32) {
                sm.c.asumP[w][p32]      += am0;
                sm.c.asumP[w][32 + p32] += am1;
            }
        }
        if (ch >= 1) {
            const int pc = ch - 1;
            bf16x8 af = *(const bf16x8*)&sm.c.aT[pc & 1][cg * 16 + col][grp * 8];
            unsigned xvb = (unsigned)(uintptr_t)
                &sm.c.x[pc % 3][(grp * 2) * TBS + (cq * 8) * CBS + col];
            #pragma unroll
            for (int hh = 0; hh < 2; ++hh) {
                u32x2 lo[4], hi[4];
                #pragma unroll
                for (int j2 = 0; j2 < 4; ++j2) {
                    const unsigned o = (unsigned)((hh * 4 + j2) * 2 * CBS);
                    asm volatile("ds_read_b64_tr_b16 %0, %1" : "=v"(lo[j2]) : "v"(xvb + o));
                    asm volatile("ds_read_b64_tr_b16 %0, %1" : "=v"(hi[j2]) : "v"(xvb + o + (unsigned)(2 * TBS)));
                }
                asm volatile("s_waitcnt lgkmcnt(0)" ::: "memory");
                __builtin_amdgcn_sched_barrier(0);
                #pragma unroll
                for (int j2 = 0; j2 < 4; ++j2) {
                    union { bf16x8 v; u32x2 u[2]; } pk;
                    pk.u[0] = lo[j2]; pk.u[1] = hi[j2];
                    acc[hh * 4 + j2] = __builtin_amdgcn_mfma_f32_16x16x32_bf16(
                        af, pk.v, acc[hh * 4 + j2], 0, 0, 0);
                }
            }
        }
        LB();
    }

    // ---- VLAD for the last chunk (7) ----
    {
        const int pc = NCH - 1;
        bf16x8 af = *(const bf16x8*)&sm.c.aT[pc & 1][cg * 16 + col][grp * 8];
        unsigned xvb = (unsigned)(uintptr_t)
            &sm.c.x[pc % 3][(grp * 2) * TBS + (cq * 8) * CBS + col];
        #pragma unroll
        for (int hh = 0; hh < 2; ++hh) {
            u32x2 lo[4], hi[4];
            #pragma unroll
            for (int j2 = 0; j2 < 4; ++j2) {
                const unsigned o = (unsigned)((hh * 4 + j2) * 2 * CBS);
                asm volatile("ds_read_b64_tr_b16 %0, %1" : "=v"(lo[j2]) : "v"(xvb + o));
                asm volatile("ds_read_b64_tr_b16 %0, %1" : "=v"(hi[j2]) : "v"(xvb + o + (unsigned)(2 * TBS)));
            }
            asm volatile("s_waitcnt lgkmcnt(0)" ::: "memory");
            __builtin_amdgcn_sched_barrier(0);
            #pragma unroll
            for (int j2 = 0; j2 < 4; ++j2) {
                union { bf16x8 v; u32x2 u[2]; } pk;
                pk.u[0] = lo[j2]; pk.u[1] = hi[j2];
                acc[hh * 4 + j2] = __builtin_amdgcn_mfma_f32_16x16x32_bf16(
                    af, pk.v, acc[hh * 4 + j2], 0, 0, 0);
            }
        }
    }
    if (tid < KK) {
        float a = 0.f;
        #pragma unroll
        for (int ww = 0; ww < 16; ++ww) a += sm.c.asumP[ww][tid];
        asumF[tid] = a;
    }
    LB();

    // ===== epilogue (R1-verified) =====
    #pragma unroll
    for (int r = 0; r < 4; ++r) {
        int cl = cg * 16 + grp * 4 + r;
        float as = asumF[cl];
        float ss = 0.f;
        #pragma unroll
        for (int j = 0; j < 8; ++j) {
            int c = cq * 128 + j * 16 + col;
            float v = acc[j][r] - as * cent[(size_t)cl * CC + c];
            acc[j][r] = v;
            ss += v * v;
        }
        ss += __shfl_xor(ss, 1); ss += __shfl_xor(ss, 2);
        ss += __shfl_xor(ss, 4); ss += __shfl_xor(ss, 8);
        if (col == 0) ssred[cq][cl] = ss;
    }
    LB();

    float contrib = 0.f;
    #pragma unroll
    for (int r = 0; r < 4; ++r) {
        int cl = cg * 16 + grp * 4 + r;
        float ss = ssred[0][cl] + ssred[1][cl] + ssred[2][cl] + ssred[3][cl];
        float inv = 1.f / fmaxf(sqrtf(ss), 1e-12f);
        #pragma unroll
        for (int j = 0; j < 8; ++j) {
            float v = acc[j][r] * inv;
            acc[j][r] = v;
            contrib += v * v;
        }
    }
    #pragma unroll
    for (int m = 1; m < 64; m <<= 1) contrib += __shfl_xor(contrib, m);
    if (lane == 0) gred[w] = contrib;
    LB();
    if (tid == 0) {
        float tot = 0.f;
        #pragma unroll
        for (int i = 0; i < 16; ++i) tot += gred[i];
        vinv_sh = 1.f / fmaxf(sqrtf(tot), 1e-12f);
    }
    LB();

    // write normalized v (bf16) to LDS — chunk arrays dead now
    {
        float vinv = vinv_sh;
        #pragma unroll
        for (int r = 0; r < 4; ++r) {
            int cl = cg * 16 + grp * 4 + r;
            #pragma unroll
            for (int j = 0; j < 8; ++j) {
                int c = cq * 128 + j * 16 + col;
                sm.e.vbuf[cl * CC + c] = f2bf(acc[j][r] * vinv);
            }
        }
    }
    LB();

    // FC: NCLS dots of length 32768
    float pacc[NCLS] = {0.f, 0.f, 0.f, 0.f};
    #pragma unroll
    for (int i = 0; i < 4; ++i) {
        int idx = i * 8192 + tid * 8;
        bf16x8 vv = *(const bf16x8*)&sm.e.vbuf[idx];
        float vf[8];
        #pragma unroll
        for (int h = 0; h < 8; ++h) {
            union { unsigned int u; float f; } cvt;
            cvt.u = ((unsigned int)(unsigned short)vv[h]) << 16;
            vf[h] = cvt.f;
        }
        #pragma unroll
        for (int nc = 0; nc < NCLS; ++nc) {
            const float* wp = fcw + (size_t)nc * (KK * CC) + idx;
            float4 w0 = *(const float4*)wp;
            float4 w1 = *(const float4*)(wp + 4);
            pacc[nc] += vf[0] * w0.x + vf[1] * w0.y + vf[2] * w0.z + vf[3] * w0.w
                      + vf[4] * w1.x + vf[5] * w1.y + vf[6] * w1.z + vf[7] * w1.w;
        }
    }
    #pragma unroll
    for (int nc = 0; nc < NCLS; ++nc) {
        #pragma unroll
        for (int m = 1; m < 64; m <<= 1) pacc[nc] += __shfl_xor(pacc[nc], m);
    }
    if (lane == 0) {
        #pragma unroll
        for (int nc = 0; nc < NCLS; ++nc) fcred[w][nc] = pacc[nc];
    }
    LB();
    if (tid < NCLS) {
        float s = fcb[tid];
        #pragma unroll
        for (int ww = 0; ww < 16; ++ww) s += fcred[ww][tid];
        out[b * NCLS + tid] = 1.f / (1.f + __expf(-s));
    }
#undef ISSUE
#undef STAGE
}

extern "C" void kernel_launch(void* const* d_in, const int* in_sizes, int n_in,
                              void* d_out, int out_size, void* d_ws, size_t ws_size,
                              hipStream_t stream) {
    const float* inp   = (const float*)d_in[0];
    const float* convw = (const float*)d_in[1];
    const float* cent  = (const float*)d_in[2];
    const float* fcw   = (const float*)d_in[3];
    const float* fcb   = (const float*)d_in[4];
    float* o = (float*)d_out;
    netvlad_kernel<<<BB, THREADS, 0, stream>>>(inp, convw, cent, fcw, fcb, o);
}

// Round 6
// 212.538 us; speedup vs baseline: 1.5581x; 1.0855x over previous
//
#include <hip/hip_runtime.h>
#include <hip/hip_bf16.h>
#include <stdint.h>

#define BB 256
#define TT 240
#define CC 512
#define KK 64
#define NCLS 4
#define CHUNK 32
#define NCH 8          // 7 full chunks + 1 half (tvalid=16)
#define THREADS 1024

// Subtiled x layout: x[tb][cb][4][16] bf16, tb=t/4 (8 per chunk), cb=c/16 (32)
// CBS=72 elems (144 B): c-block bank stride 36 words == 4 mod 32 (verified R1)
// TBS=2312 elems (4624 B): t-block stride == 4 mod 32 (verified R1)
#define CBS 72
#define TBS 2312
#define XELEMS (8 * TBS)   // 18,496 elems = 36,992 B per 32-t buffer

typedef __attribute__((ext_vector_type(8))) short bf16x8;
typedef __attribute__((ext_vector_type(4))) float f32x4;
typedef __attribute__((ext_vector_type(2))) unsigned int u32x2;

__device__ __forceinline__ unsigned short f2bf(float f) {
    union { float f; unsigned int i; } x; x.f = f;
    unsigned int r = x.i + 0x7FFFu + ((x.i >> 16) & 1u);  // RNE, finite only
    return (unsigned short)(r >> 16);
}
__device__ __forceinline__ unsigned int pk2cvt(float lo, float hi) {
    union { __hip_bfloat162 h; unsigned int u; } c;
    c.h = __float22bfloat162_rn(float2{lo, hi});
    return c.u;
}
// LDS-only barrier: doesn't drain vmcnt (global prefetch stays in flight)
__device__ __forceinline__ void LB() {
    asm volatile("s_waitcnt lgkmcnt(0)\n\ts_barrier" ::: "memory");
}

struct alignas(16) SMemChunk {
    unsigned short x[3][XELEMS];    // triple-buffered subtiled x  (110,976 B)
    float logitsP[2][CHUNK][67];    // k-half partial logits       ( 17,152 B)
    unsigned short aT[2][KK][40];   // a' = a*rinv bf16, 2 slots   ( 10,240 B)
    float sumsqP[2][CHUNK][16];     // folded sumsq partials       (  4,096 B)
    float asumP[16][KK];            // per-wave asum accumulators  (  4,096 B)
};                                  // 146,560 B
struct alignas(16) SMemEpi { unsigned short vbuf[KK * CC]; };  // 64 KB
union SMemU { SMemChunk c; SMemEpi e; };

__device__ __forceinline__ void stage_row(unsigned short* xb, float* ssp,
        float4 u0, float4 u1, int t, int c8, int lane, int tv) {
    uint4 val = (uint4){pk2cvt(u0.x, u0.y), pk2cvt(u0.z, u0.w),
                        pk2cvt(u1.x, u1.y), pk2cvt(u1.z, u1.w)};
    float s = u0.x*u0.x + u0.y*u0.y + u0.z*u0.z + u0.w*u0.w
            + u1.x*u1.x + u1.y*u1.y + u1.z*u1.z + u1.w*u1.w;
    if (t >= tv) { val = (uint4){0u,0u,0u,0u}; s = 0.f; }
    int off = (t >> 2) * TBS + (c8 >> 4) * CBS + (t & 3) * 16 + (c8 & 15);
    *(uint4*)&xb[off] = val;
    s += __shfl_xor(s, 16); s += __shfl_xor(s, 32);
    if (lane < 16) ssp[t * 16 + lane] = s;   // 16 partials per row
}

__global__ __launch_bounds__(THREADS, 4) void netvlad_kernel(
    const float* __restrict__ inp,    // [B,T,C]
    const float* __restrict__ convw,  // [K,C]
    const float* __restrict__ cent,   // [K,C]
    const float* __restrict__ fcw,    // [NC, K*C]
    const float* __restrict__ fcb,    // [NC]
    float* __restrict__ out)          // [B,NC]
{
    __shared__ SMemU sm;
    __shared__ float asumF[KK];
    __shared__ float ssred[4][KK];
    __shared__ float gred[16];
    __shared__ float fcred[16][NCLS];
    __shared__ float vinv_sh;

    const int tid  = threadIdx.x;
    const int b    = blockIdx.x;
    const int w    = tid >> 6;       // wave 0..15
    const int lane = tid & 63;
    const int grp  = (lane >> 4) & 3;
    const int col  = lane & 15;
    const int cg   = w & 3;          // cluster group (logits/VLAD/epilogue)
    const int th   = (w >> 2) & 1;   // logits t-tile
    const int kh   = w >> 3;         // logits k-half
    const int cq   = w >> 2;         // VLAD c-quarter

    ((float*)sm.c.asumP)[tid] = 0.f;   // 16*64 = 1024 entries

    f32x4 acc[8];
    #pragma unroll
    for (int j = 0; j < 8; ++j) acc[j] = (f32x4){0.f, 0.f, 0.f, 0.f};

    const size_t ibase = (size_t)b * (TT * CC);
    const int c8 = lane << 3;

#define ISSUE(nc) do { \
        int tg0_ = (nc) * CHUNK + w;      if (tg0_ > TT - 1) tg0_ = TT - 1; \
        int tg1_ = (nc) * CHUNK + w + 16; if (tg1_ > TT - 1) tg1_ = TT - 1; \
        const float* p0_ = inp + ibase + (size_t)tg0_ * CC + c8; \
        const float* p1_ = inp + ibase + (size_t)tg1_ * CC + c8; \
        pre[0] = *(const float4*)p0_; pre[1] = *(const float4*)(p0_ + 4); \
        pre[2] = *(const float4*)p1_; pre[3] = *(const float4*)(p1_ + 4); \
    } while (0)

#define STAGE(nc) do { \
        const int tv_ = (TT - (nc) * CHUNK < CHUNK) ? (TT - (nc) * CHUNK) : CHUNK; \
        unsigned short* xb_ = sm.c.x[(nc) % 3]; \
        float* ssp_ = &sm.c.sumsqP[(nc) & 1][0][0]; \
        stage_row(xb_, ssp_, pre[0], pre[1], w,      c8, lane, tv_); \
        stage_row(xb_, ssp_, pre[2], pre[3], w + 16, c8, lane, tv_); \
    } while (0)

    // ---- prologue: issue chunk 0; cw setup; stage 0; issue chunk 1 ----
    float4 pre[4];
    ISSUE(0);

    // conv_w slice: clusters 16cg..+16, k-half kh (8 x bf16x8 = 32 VGPRs)
    bf16x8 cw[8];
    #pragma unroll
    for (int s = 0; s < 8; ++s) {
        const float* p = convw + (size_t)(cg * 16 + col) * CC + (kh * 8 + s) * 32 + grp * 8;
        float4 a0 = *(const float4*)p;
        float4 a1 = *(const float4*)(p + 4);
        bf16x8 v;
        v[0] = (short)f2bf(a0.x); v[1] = (short)f2bf(a0.y);
        v[2] = (short)f2bf(a0.z); v[3] = (short)f2bf(a0.w);
        v[4] = (short)f2bf(a1.x); v[5] = (short)f2bf(a1.y);
        v[6] = (short)f2bf(a1.z); v[7] = (short)f2bf(a1.w);
        cw[s] = v;
    }

    STAGE(0);
    ISSUE(1);
    LB();

    for (int ch = 0; ch < NCH; ++ch) {
        // ---- P1: stage(ch+1) from pre, re-issue pre<-(ch+2), logits(ch) ----
        if (ch + 1 < NCH) STAGE(ch + 1);
        if (ch + 2 < NCH) ISSUE(ch + 2);
        {
            const unsigned short* xb = sm.c.x[ch % 3];
            f32x4 lt = (f32x4){0.f, 0.f, 0.f, 0.f};
            const int t = th * 16 + col;
            const int rb = (t >> 2) * TBS + (t & 3) * 16 + ((grp & 1) << 3);
            #pragma unroll
            for (int s = 0; s < 8; ++s) {
                const bf16x8 bb = *(const bf16x8*)&xb[rb + ((kh * 8 + s) * 2 + (grp >> 1)) * CBS];
                lt = __builtin_amdgcn_mfma_f32_16x16x32_bf16(cw[s], bb, lt, 0, 0, 0);
            }
            #pragma unroll
            for (int r = 0; r < 4; ++r)
                sm.c.logitsP[kh][t][cg * 16 + grp * 4 + r] = lt[r];
        }
        LB();  // logitsP(ch) + x(ch+1) + sumsq(ch+1) ready

        // ---- P2: softmax(ch) [all 16 waves, folded asum] + VLAD(ch-1) ----
        {
            const int tv = (TT - ch * CHUNK < CHUNK) ? (TT - ch * CHUNK) : CHUNK;
            const int t = tid >> 5;        // 0..31 (32 threads per row)
            const int p32 = lane & 31;     // clusters p32 and 32+p32
            float ss = (p32 < 16) ? sm.c.sumsqP[ch & 1][t][p32] : 0.f;
            float l0 = sm.c.logitsP[0][t][p32]      + sm.c.logitsP[1][t][p32];
            float l1 = sm.c.logitsP[0][t][32 + p32] + sm.c.logitsP[1][t][32 + p32];
            float lmax = fmaxf(l0, l1);
            #pragma unroll
            for (int m = 1; m < 32; m <<= 1) {
                lmax = fmaxf(lmax, __shfl_xor(lmax, m));
                ss  += __shfl_xor(ss, m);
            }
            float rinv = 1.f / fmaxf(sqrtf(ss), 1e-12f);
            rinv = (t < tv) ? rinv : 0.f;
            float m0 = lmax * rinv;
            l0 = __expf(l0 * rinv - m0);
            l1 = __expf(l1 * rinv - m0);
            float es = l0 + l1;
            #pragma unroll
            for (int m = 1; m < 32; m <<= 1) es += __shfl_xor(es, m);
            float is = 1.f / es;
            float a0 = l0 * is, a1 = l1 * is;
            sm.c.aT[ch & 1][p32][t]      = (unsigned short)f2bf(a0 * rinv);  // 0 if masked
            sm.c.aT[ch & 1][32 + p32][t] = (unsigned short)f2bf(a1 * rinv);
            float am0 = (t < tv) ? a0 : 0.f;
            float am1 = (t < tv) ? a1 : 0.f;
            am0 += __shfl_xor(am0, 32);
            am1 += __shfl_xor(am1, 32);
            if (lane < 32) {
                sm.c.asumP[w][p32]      += am0;
                sm.c.asumP[w][32 + p32] += am1;
            }
        }
        if (ch >= 1) {
            const int pc = ch - 1;
            bf16x8 af = *(const bf16x8*)&sm.c.aT[pc & 1][cg * 16 + col][grp * 8];
            unsigned xvb = (unsigned)(uintptr_t)
                &sm.c.x[pc % 3][(grp * 2) * TBS + (cq * 8) * CBS + col];
            #pragma unroll
            for (int hh = 0; hh < 2; ++hh) {
                u32x2 lo[4], hi[4];
                #pragma unroll
                for (int j2 = 0; j2 < 4; ++j2) {
                    const unsigned o = (unsigned)((hh * 4 + j2) * 2 * CBS);
                    asm volatile("ds_read_b64_tr_b16 %0, %1" : "=v"(lo[j2]) : "v"(xvb + o));
                    asm volatile("ds_read_b64_tr_b16 %0, %1" : "=v"(hi[j2]) : "v"(xvb + o + (unsigned)(2 * TBS)));
                }
                asm volatile("s_waitcnt lgkmcnt(0)" ::: "memory");
                __builtin_amdgcn_sched_barrier(0);
                #pragma unroll
                for (int j2 = 0; j2 < 4; ++j2) {
                    union { bf16x8 v; u32x2 u[2]; } pk;
                    pk.u[0] = lo[j2]; pk.u[1] = hi[j2];
                    acc[hh * 4 + j2] = __builtin_amdgcn_mfma_f32_16x16x32_bf16(
                        af, pk.v, acc[hh * 4 + j2], 0, 0, 0);
                }
            }
        }
        LB();
    }

    // ---- VLAD for the last chunk (7) ----
    {
        const int pc = NCH - 1;
        bf16x8 af = *(const bf16x8*)&sm.c.aT[pc & 1][cg * 16 + col][grp * 8];
        unsigned xvb = (unsigned)(uintptr_t)
            &sm.c.x[pc % 3][(grp * 2) * TBS + (cq * 8) * CBS + col];
        #pragma unroll
        for (int hh = 0; hh < 2; ++hh) {
            u32x2 lo[4], hi[4];
            #pragma unroll
            for (int j2 = 0; j2 < 4; ++j2) {
                const unsigned o = (unsigned)((hh * 4 + j2) * 2 * CBS);
                asm volatile("ds_read_b64_tr_b16 %0, %1" : "=v"(lo[j2]) : "v"(xvb + o));
                asm volatile("ds_read_b64_tr_b16 %0, %1" : "=v"(hi[j2]) : "v"(xvb + o + (unsigned)(2 * TBS)));
            }
            asm volatile("s_waitcnt lgkmcnt(0)" ::: "memory");
            __builtin_amdgcn_sched_barrier(0);
            #pragma unroll
            for (int j2 = 0; j2 < 4; ++j2) {
                union { bf16x8 v; u32x2 u[2]; } pk;
                pk.u[0] = lo[j2]; pk.u[1] = hi[j2];
                acc[hh * 4 + j2] = __builtin_amdgcn_mfma_f32_16x16x32_bf16(
                    af, pk.v, acc[hh * 4 + j2], 0, 0, 0);
            }
        }
    }
    if (tid < KK) {
        float a = 0.f;
        #pragma unroll
        for (int ww = 0; ww < 16; ++ww) a += sm.c.asumP[ww][tid];
        asumF[tid] = a;
    }
    LB();

    // ===== epilogue (R1-verified) =====
    #pragma unroll
    for (int r = 0; r < 4; ++r) {
        int cl = cg * 16 + grp * 4 + r;
        float as = asumF[cl];
        float ss = 0.f;
        #pragma unroll
        for (int j = 0; j < 8; ++j) {
            int c = cq * 128 + j * 16 + col;
            float v = acc[j][r] - as * cent[(size_t)cl * CC + c];
            acc[j][r] = v;
            ss += v * v;
        }
        ss += __shfl_xor(ss, 1); ss += __shfl_xor(ss, 2);
        ss += __shfl_xor(ss, 4); ss += __shfl_xor(ss, 8);
        if (col == 0) ssred[cq][cl] = ss;
    }
    LB();

    float contrib = 0.f;
    #pragma unroll
    for (int r = 0; r < 4; ++r) {
        int cl = cg * 16 + grp * 4 + r;
        float ss = ssred[0][cl] + ssred[1][cl] + ssred[2][cl] + ssred[3][cl];
        float inv = 1.f / fmaxf(sqrtf(ss), 1e-12f);
        #pragma unroll
        for (int j = 0; j < 8; ++j) {
            float v = acc[j][r] * inv;
            acc[j][r] = v;
            contrib += v * v;
        }
    }
    #pragma unroll
    for (int m = 1; m < 64; m <<= 1) contrib += __shfl_xor(contrib, m);
    if (lane == 0) gred[w] = contrib;
    LB();
    if (tid == 0) {
        float tot = 0.f;
        #pragma unroll
        for (int i = 0; i < 16; ++i) tot += gred[i];
        vinv_sh = 1.f / fmaxf(sqrtf(tot), 1e-12f);
    }
    LB();

    // write normalized v (bf16) to LDS — chunk arrays dead now
    {
        float vinv = vinv_sh;
        #pragma unroll
        for (int r = 0; r < 4; ++r) {
            int cl = cg * 16 + grp * 4 + r;
            #pragma unroll
            for (int j = 0; j < 8; ++j) {
                int c = cq * 128 + j * 16 + col;
                sm.e.vbuf[cl * CC + c] = f2bf(acc[j][r] * vinv);
            }
        }
    }
    LB();

    // FC: NCLS dots of length 32768
    float pacc[NCLS] = {0.f, 0.f, 0.f, 0.f};
    #pragma unroll
    for (int i = 0; i < 4; ++i) {
        int idx = i * 8192 + tid * 8;
        bf16x8 vv = *(const bf16x8*)&sm.e.vbuf[idx];
        float vf[8];
        #pragma unroll
        for (int h = 0; h < 8; ++h) {
            union { unsigned int u; float f; } cvt;
            cvt.u = ((unsigned int)(unsigned short)vv[h]) << 16;
            vf[h] = cvt.f;
        }
        #pragma unroll
        for (int nc = 0; nc < NCLS; ++nc) {
            const float* wp = fcw + (size_t)nc * (KK * CC) + idx;
            float4 w0 = *(const float4*)wp;
            float4 w1 = *(const float4*)(wp + 4);
            pacc[nc] += vf[0] * w0.x + vf[1] * w0.y + vf[2] * w0.z + vf[3] * w0.w
                      + vf[4] * w1.x + vf[5] * w1.y + vf[6] * w1.z + vf[7] * w1.w;
        }
    }
    #pragma unroll
    for (int nc = 0; nc < NCLS; ++nc) {
        #pragma unroll
        for (int m = 1; m < 64; m <<= 1) pacc[nc] += __shfl_xor(pacc[nc], m);
    }
    if (lane == 0) {
        #pragma unroll
        for (int nc = 0; nc < NCLS; ++nc) fcred[w][nc] = pacc[nc];
    }
    LB();
    if (tid < NCLS) {
        float s = fcb[tid];
        #pragma unroll
        for (int ww = 0; ww < 16; ++ww) s += fcred[ww][tid];
        out[b * NCLS + tid] = 1.f / (1.f + __expf(-s));
    }
#undef ISSUE
#undef STAGE
}

extern "C" void kernel_launch(void* const* d_in, const int* in_sizes, int n_in,
                              void* d_out, int out_size, void* d_ws, size_t ws_size,
                              hipStream_t stream) {
    const float* inp   = (const float*)d_in[0];
    const float* convw = (const float*)d_in[1];
    const float* cent  = (const float*)d_in[2];
    const float* fcw   = (const float*)d_in[3];
    const float* fcb   = (const float*)d_in[4];
    float* o = (float*)d_out;
    netvlad_kernel<<<BB, THREADS, 0, stream>>>(inp, convw, cent, fcw, fcb, o);
}